// Round 4
// baseline (516.427 us; speedup 1.0000x reference)
//
#include <hip/hip_runtime.h>
#include <stdint.h>

// ---------------------------------------------------------------------------
// Transformer block: LN1 -> QKV GEMM -> repack K/V -> flash-MFMA attention
//                    -> proj(+res) -> LN2 -> MLP1(GELU) -> MLP2(+res)
// All matmuls: bf16 inputs, fp32 MFMA accumulation (16x16x32_bf16).
// Fragment layouts (learn_hip m89/m91):
//   A-frag:  A[m = lane&15][k = (lane>>4)*8 + j]   (8 bf16, contiguous in k)
//   B-frag:  B[k = (lane>>4)*8 + j][n = lane&15]   (= Bt[n][k], contiguous k)
//   C/D   :  D[m = (lane>>4)*4 + r][n = lane&15]
// Attention: S^T = K@Q^T, softmax rows per-lane (q = lane&15). K/V fragments
// loaded DIRECTLY from per-head packed kT/vT (L2-resident; no LDS staging,
// no barriers in the k-loop). Only P^T round-trips through per-wave LDS.
// GEMM: BK=64, global_load_lds w16, XOR chunk swizzle (phys = log ^ (row&7))
// applied on the global-source side so the LDS dest stays lane-linear.
// ---------------------------------------------------------------------------

#define DIMC 1024
#define HIDN 4096
#define SEQ  2048
#define TOK  4096   // B*N = 2*2048

typedef __bf16 bf16x8 __attribute__((ext_vector_type(8)));
typedef float  f32x4  __attribute__((ext_vector_type(4)));
typedef unsigned short ushort8 __attribute__((ext_vector_type(8)));

__device__ inline unsigned short f2bf(float f) {
  union { float f; unsigned u; } v; v.f = f;
  unsigned u = v.u;
  return (unsigned short)((u + 0x7fffu + ((u >> 16) & 1u)) >> 16);  // RNE
}

// HW packed fp32->bf16 (CDNA3+): lo = cvt(a), hi = cvt(b)
__device__ inline unsigned cvt_pk_bf16(float a, float b) {
  unsigned r;
  asm("v_cvt_pk_bf16_f32 %0, %1, %2" : "=v"(r) : "v"(a), "v"(b));
  return r;
}

__device__ inline f32x4 mfma_bf16(bf16x8 a, bf16x8 b, f32x4 c) {
  return __builtin_amdgcn_mfma_f32_16x16x32_bf16(a, b, c, 0, 0, 0);
}

// async global->LDS, 16B per lane; LDS dest = wave-uniform base + lane*16
typedef const __attribute__((address_space(1))) unsigned int* as1_u32p;
typedef __attribute__((address_space(3))) unsigned int* as3_u32p;
__device__ inline void gload_lds16(const unsigned short* g, unsigned short* l) {
  __builtin_amdgcn_global_load_lds((as1_u32p)(const void*)g, (as3_u32p)(void*)l,
                                   16, 0, 0);
}

// ---------------------------------------------------------------------------
// All 4 weight transposes in one launch: w[K][N] fp32 -> wt[N][K] bf16
// segments: qkv 96x32 tiles | proj 32x32 | w1 128x32 | w2 32x128
// ---------------------------------------------------------------------------
__global__ __launch_bounds__(256)
void transpose_cast4(const float* __restrict__ wa, unsigned short* __restrict__ ta,
                     const float* __restrict__ wb, unsigned short* __restrict__ tb,
                     const float* __restrict__ wc, unsigned short* __restrict__ tc,
                     const float* __restrict__ wd, unsigned short* __restrict__ td) {
  __shared__ float tile[32][33];
  const int bid = blockIdx.x;
  const float* w; unsigned short* wt; int K, N, bx, by;
  if (bid < 3072)      { w = wa; wt = ta; K = 1024; N = 3072; bx = bid % 96;  by = bid / 96; }
  else if (bid < 4096) { int i = bid - 3072; w = wb; wt = tb; K = 1024; N = 1024; bx = i % 32;  by = i / 32; }
  else if (bid < 8192) { int i = bid - 4096; w = wc; wt = tc; K = 1024; N = 4096; bx = i % 128; by = i / 128; }
  else                 { int i = bid - 8192; w = wd; wt = td; K = 4096; N = 1024; bx = i % 32;  by = i / 32; }
  const int k0 = by * 32;
  const int n0 = bx * 32;
  const int tx = threadIdx.x & 31;
  const int ty = threadIdx.x >> 5;  // 0..7
#pragma unroll
  for (int i = 0; i < 4; i++)
    tile[ty + i * 8][tx] = w[(size_t)(k0 + ty + i * 8) * N + n0 + tx];
  __syncthreads();
#pragma unroll
  for (int i = 0; i < 4; i++)
    wt[(size_t)(n0 + ty + i * 8) * K + k0 + tx] = f2bf(tile[tx][ty + i * 8]);
}

// ---------------------------------------------------------------------------
// LayerNorm: x[rows][1024] fp32 -> out bf16
// ---------------------------------------------------------------------------
__global__ __launch_bounds__(256)
void ln_kernel(const float* __restrict__ x, const float* __restrict__ g,
               const float* __restrict__ b, unsigned short* __restrict__ out) {
  const int row = blockIdx.x;
  const int tid = threadIdx.x;
  const float4* xr = (const float4*)&x[(size_t)row * DIMC];
  float4 v = xr[tid];
  float s  = v.x + v.y + v.z + v.w;
  float sq = v.x * v.x + v.y * v.y + v.z * v.z + v.w * v.w;
#pragma unroll
  for (int off = 32; off > 0; off >>= 1) {
    s  += __shfl_xor(s, off, 64);
    sq += __shfl_xor(sq, off, 64);
  }
  __shared__ float red[8];
  if ((tid & 63) == 0) { red[tid >> 6] = s; red[4 + (tid >> 6)] = sq; }
  __syncthreads();
  s  = red[0] + red[1] + red[2] + red[3];
  sq = red[4] + red[5] + red[6] + red[7];
  const float mu  = s * (1.0f / DIMC);
  const float var = sq * (1.0f / DIMC) - mu * mu;
  const float rs  = rsqrtf(var + 1e-5f);
  const int c = tid * 4;
  float vv[4] = {v.x, v.y, v.z, v.w};
#pragma unroll
  for (int j = 0; j < 4; j++)
    out[(size_t)row * DIMC + c + j] = f2bf((vv[j] - mu) * rs * g[c + j] + b[c + j]);
}

// ---------------------------------------------------------------------------
// GEMM: C[M][N] = A[M][K] @ B, Bt[N][K] bf16. 128xTN tile, BK=64, 4 waves.
// global_load_lds w16 staging; XOR chunk swizzle on the global source so
// ds_read fragments are conflict-light while LDS dest stays lane-linear.
// EPI: 0 = bf16 store; 1 = +bias+res fp32; 2 = gelu(+bias) bf16
// ---------------------------------------------------------------------------
template <int EPI, int TN>
__global__ __launch_bounds__(256, (TN == 64) ? 4 : 2)
void gemm_bt(const unsigned short* __restrict__ A,
             const unsigned short* __restrict__ Bt,
             float* __restrict__ Cf, unsigned short* __restrict__ Cb,
             const float* __restrict__ bias, const float* __restrict__ res,
             int M, int N, int K) {
  constexpr int NU = TN / 32;            // B n-tiles per wave
  constexpr int BP = TN / 32;            // B staging passes (32 rows each)
  __shared__ unsigned short As[128 * 64];
  __shared__ unsigned short Bs[TN * 64];
  const int tid  = threadIdx.x;
  const int lane = tid & 63;
  const int wave = tid >> 6;
  const int m0 = blockIdx.y * 128;
  const int n0 = blockIdx.x * TN;
  const int wm = (wave >> 1) * 64;
  const int wn = (wave & 1) * (TN / 2);
  const int lm = lane & 15;
  const int lg = lane >> 4;
  const int r8 = tid >> 3;     // 0..31 row within pass
  const int c8 = tid & 7;      // phys 16B chunk within 128B row
  const int csrc = ((c8 ^ (r8 & 7)) * 8);  // logical elem offset (swizzled)

  const unsigned short* gA = &A [(size_t)(m0 + r8) * K + csrc];
  const unsigned short* gB = &Bt[(size_t)(n0 + r8) * K + csrc];

  f32x4 acc[4][NU];
#pragma unroll
  for (int t = 0; t < 4; t++)
#pragma unroll
    for (int u = 0; u < NU; u++) acc[t][u] = {0.f, 0.f, 0.f, 0.f};

  const int x0 = (lg ^ (lm & 7)) * 8;        // sub 0 phys chunk offset (elems)
  const int x1 = ((4 + lg) ^ (lm & 7)) * 8;  // sub 1

  for (int k0 = 0; k0 < K; k0 += 64) {
    __syncthreads();                 // prior tile's LDS reads done
#pragma unroll
    for (int p = 0; p < 4; p++)
      gload_lds16(gA + (size_t)p * 32 * K + k0, &As[p * 2048 + wave * 512]);
#pragma unroll
    for (int p = 0; p < BP; p++)
      gload_lds16(gB + (size_t)p * 32 * K + k0, &Bs[p * 2048 + wave * 512]);
    __syncthreads();                 // drains vmcnt before barrier
#pragma unroll
    for (int sub = 0; sub < 2; sub++) {
      const int xo = sub ? x1 : x0;
      bf16x8 af[4], bfr[NU];
#pragma unroll
      for (int t = 0; t < 4; t++)  af[t]  = *(const bf16x8*)&As[(wm + t * 16 + lm) * 64 + xo];
#pragma unroll
      for (int u = 0; u < NU; u++) bfr[u] = *(const bf16x8*)&Bs[(wn + u * 16 + lm) * 64 + xo];
#pragma unroll
      for (int t = 0; t < 4; t++)
#pragma unroll
        for (int u = 0; u < NU; u++)
          acc[t][u] = mfma_bf16(af[t], bfr[u], acc[t][u]);
    }
  }

#pragma unroll
  for (int t = 0; t < 4; t++) {
    const int row = m0 + wm + t * 16 + lg * 4;
#pragma unroll
    for (int u = 0; u < NU; u++) {
      const int col = n0 + wn + u * 16 + lm;
#pragma unroll
      for (int r = 0; r < 4; r++) {
        float v = acc[t][u][r];
        size_t idx = (size_t)(row + r) * N + col;
        if (EPI == 0) {
          Cb[idx] = f2bf(v);
        } else if (EPI == 1) {
          Cf[idx] = v + bias[col] + res[idx];
        } else {
          float xg = v + bias[col];
          Cb[idx] = f2bf(0.5f * xg * (1.0f + erff(xg * 0.70710678118654752f)));
        }
      }
    }
  }
}

// ---------------------------------------------------------------------------
// Repack K,V per head: kT[bh][key][d] (head-gather), vT[bh][d][key]
// (transpose via LDS). qkv[token][3072], K at +1024, V at +2048, head h*64.
// ---------------------------------------------------------------------------
__global__ __launch_bounds__(256)
void repack_kv(const unsigned short* __restrict__ qkv,
               unsigned short* __restrict__ kT, unsigned short* __restrict__ vT) {
  const int kt = blockIdx.x;
  const int bh = blockIdx.y;
  const int b = bh >> 4, h = bh & 15;
  const int tid = threadIdx.x;
  __shared__ unsigned short tile[64 * 72];
  const int tok = tid >> 2;       // 0..63
  const int ch  = tid & 3;        // chunks ch, ch+4 (8 d each)
  const size_t srow = (size_t)(b * SEQ + kt * 64 + tok) * 3072 + h * 64;
  // K: straight copy
  ushort8 ka = *(const ushort8*)&qkv[srow + 1024 + ch * 8];
  ushort8 kb = *(const ushort8*)&qkv[srow + 1024 + 32 + ch * 8];
  const size_t kdst = ((size_t)bh * SEQ + kt * 64 + tok) * 64;
  *(ushort8*)&kT[kdst + ch * 8] = ka;
  *(ushort8*)&kT[kdst + 32 + ch * 8] = kb;
  // V: transpose via LDS
  ushort8 va = *(const ushort8*)&qkv[srow + 2048 + ch * 8];
  ushort8 vb = *(const ushort8*)&qkv[srow + 2048 + 32 + ch * 8];
  *(ushort8*)&tile[tok * 72 + ch * 8] = va;
  *(ushort8*)&tile[tok * 72 + 32 + ch * 8] = vb;
  __syncthreads();
  const int d = tid >> 2;         // 0..63
  ushort8 o0, o1;
#pragma unroll
  for (int j = 0; j < 8; j++) {
    o0[j] = tile[(ch * 8 + j) * 72 + d];
    o1[j] = tile[((ch + 4) * 8 + j) * 72 + d];
  }
  const size_t vdst = ((size_t)bh * 64 + d) * SEQ + kt * 64;
  *(ushort8*)&vT[vdst + ch * 8] = o0;
  *(ushort8*)&vT[vdst + 32 + ch * 8] = o1;
}

// ---------------------------------------------------------------------------
// Flash attention, transposed scores, ZERO-barrier k-loop. Block = (bh, 64
// q-rows); wave = 16 q-rows, fully independent. K/V fragments loaded straight
// from L2-resident kT/vT; only P^T round-trips through per-wave LDS.
// grid(x=bh, y=qt): same-bh blocks land on one XCD (i%8 heuristic) so each
// XCD's working set is 4 bh * (kT+vT) = 4 MB = its L2.
// ---------------------------------------------------------------------------
__global__ __launch_bounds__(256)
void attn_kernel(const unsigned short* __restrict__ qkv,
                 const unsigned short* __restrict__ kT,
                 const unsigned short* __restrict__ vT,
                 unsigned short* __restrict__ out) {
  const int bh = blockIdx.x;
  const int qt = blockIdx.y;
  const int b  = bh >> 4;
  const int h  = bh & 15;
  const int tid  = threadIdx.x;
  const int lane = tid & 63;
  const int wave = tid >> 6;
  const int lm = lane & 15;
  const int lg = lane >> 4;

  __shared__ unsigned short Ps[4][16 * 72];     // per-wave P^T[q][key], +8 pad

  const int qrow_base = b * SEQ + qt * 64 + wave * 16;
  bf16x8 qb[2];  // B-frag: Bt[n=q][k=d] = Q natural
#pragma unroll
  for (int c = 0; c < 2; c++)
    qb[c] = *(const bf16x8*)&qkv[(size_t)(qrow_base + lm) * 3072 + h * 64 + c * 32 + lg * 8];

  f32x4 o[4];   // O^T accum: m = d (4 tiles of 16), n = q = lm
#pragma unroll
  for (int dt = 0; dt < 4; dt++) o[dt] = {0.f, 0.f, 0.f, 0.f};
  float mi = -1e30f, li = 0.f;   // per-lane scalars (row lm), log2 domain
  const float LC = 0.125f * 1.44269504088896f;  // scale * log2(e)

  const unsigned short* kbp = &kT[(size_t)bh * SEQ * 64];
  const unsigned short* vbp = &vT[(size_t)bh * 64 * SEQ];

  for (int kt = 0; kt < SEQ / 64; kt++) {
    // S^T[key][q]: A = K rows direct from L2 (A-frag == kT natural layout)
    const unsigned short* kp = kbp + (size_t)kt * 64 * 64;
    f32x4 st[4];
#pragma unroll
    for (int u = 0; u < 4; u++) {
      bf16x8 ka0 = *(const bf16x8*)&kp[(u * 16 + lm) * 64 + lg * 8];
      bf16x8 ka1 = *(const bf16x8*)&kp[(u * 16 + lm) * 64 + 32 + lg * 8];
      f32x4 z = {0.f, 0.f, 0.f, 0.f};
      z = mfma_bf16(ka0, qb[0], z);
      z = mfma_bf16(ka1, qb[1], z);
      st[u] = z;
    }

    // online softmax, row = lm; in-lane reduce + shfl_xor(16,32)
    float mx = -1e30f;
#pragma unroll
    for (int u = 0; u < 4; u++)
#pragma unroll
      for (int r = 0; r < 4; r++) mx = fmaxf(mx, st[u][r]);
    mx = fmaxf(mx, __shfl_xor(mx, 16, 64));
    mx = fmaxf(mx, __shfl_xor(mx, 32, 64));
    const float mnew = fmaxf(mi, mx * LC);
    const float alpha = exp2f(mi - mnew);
    float ps = 0.f;
#pragma unroll
    for (int u = 0; u < 4; u++)
#pragma unroll
      for (int r = 0; r < 4; r++) {
        float p = exp2f(fmaf(st[u][r], LC, -mnew));
        st[u][r] = p;
        ps += p;
      }
    ps += __shfl_xor(ps, 16, 64);
    ps += __shfl_xor(ps, 32, 64);
    li = li * alpha + ps;
    mi = mnew;
#pragma unroll
    for (int dt = 0; dt < 4; dt++) o[dt] *= alpha;

    // P^T (C-layout) -> Ps[q=lm][key], HW packed cvt + b64 writes (in-wave)
#pragma unroll
    for (int u = 0; u < 4; u++) {
      uint2 pk;
      pk.x = cvt_pk_bf16(st[u][0], st[u][1]);
      pk.y = cvt_pk_bf16(st[u][2], st[u][3]);
      *(uint2*)&Ps[wave][lm * 72 + u * 16 + lg * 4] = pk;
    }

    // O^T += V^T @ P^T : A = vT rows direct from L2
    const unsigned short* vp = vbp + kt * 64;
#pragma unroll
    for (int kc = 0; kc < 2; kc++) {
      bf16x8 pb = *(const bf16x8*)&Ps[wave][lm * 72 + kc * 32 + lg * 8];
#pragma unroll
      for (int dt = 0; dt < 4; dt++) {
        bf16x8 va = *(const bf16x8*)&vp[(size_t)(dt * 16 + lm) * SEQ + kc * 32 + lg * 8];
        o[dt] = mfma_bf16(va, pb, o[dt]);
      }
    }
  }

  const float inv = 1.0f / li;
#pragma unroll
  for (int dt = 0; dt < 4; dt++) {
    uint2 ok;
    ok.x = cvt_pk_bf16(o[dt][0] * inv, o[dt][1] * inv);
    ok.y = cvt_pk_bf16(o[dt][2] * inv, o[dt][3] * inv);
    *(uint2*)&out[(size_t)(qrow_base + lm) * DIMC + h * 64 + dt * 16 + lg * 4] = ok;
  }
}

// ---------------------------------------------------------------------------
extern "C" void kernel_launch(void* const* d_in, const int* in_sizes, int n_in,
                              void* d_out, int out_size, void* d_ws, size_t ws_size,
                              hipStream_t stream) {
  const float* x      = (const float*)d_in[0];
  const float* ln1_g  = (const float*)d_in[1];
  const float* ln1_b  = (const float*)d_in[2];
  const float* w_qkv  = (const float*)d_in[3];
  const float* w_proj = (const float*)d_in[4];
  const float* b_proj = (const float*)d_in[5];
  const float* ln2_g  = (const float*)d_in[6];
  const float* ln2_b  = (const float*)d_in[7];
  const float* w1     = (const float*)d_in[8];
  const float* b1     = (const float*)d_in[9];
  const float* w2     = (const float*)d_in[10];
  const float* b2     = (const float*)d_in[11];
  float* out = (float*)d_out;

  char* ws = (char*)d_ws;
  size_t off = 0;
  auto alloc = [&](size_t bytes) { void* p = ws + off; off += (bytes + 255) & ~(size_t)255; return p; };
  unsigned short* wqkvT = (unsigned short*)alloc((size_t)3072 * 1024 * 2);
  unsigned short* wprjT = (unsigned short*)alloc((size_t)1024 * 1024 * 2);
  unsigned short* w1T   = (unsigned short*)alloc((size_t)4096 * 1024 * 2);
  unsigned short* w2T   = (unsigned short*)alloc((size_t)1024 * 4096 * 2);
  unsigned short* hb    = (unsigned short*)alloc((size_t)TOK * 1024 * 2);
  unsigned short* qkvb  = (unsigned short*)alloc((size_t)TOK * 3072 * 2);
  unsigned short* attnb = (unsigned short*)alloc((size_t)TOK * 1024 * 2);
  float*          x1    = (float*)         alloc((size_t)TOK * 1024 * 4);
  unsigned short* hidb  = (unsigned short*)alloc((size_t)TOK * 4096 * 2);
  // kT/vT overlay hidb (32MB >= 16MB): attn finishes before MLP1 writes hidb
  unsigned short* kT = hidb;                              // 8 MB
  unsigned short* vT = hidb + (size_t)32 * SEQ * 64;      // 8 MB

  transpose_cast4<<<12288, 256, 0, stream>>>(w_qkv, wqkvT, w_proj, wprjT,
                                             w1, w1T, w2, w2T);
  ln_kernel<<<TOK, 256, 0, stream>>>(x, ln1_g, ln1_b, hb);
  gemm_bt<0, 128><<<dim3(3072 / 128, TOK / 128), 256, 0, stream>>>(
      hb, wqkvT, nullptr, qkvb, nullptr, nullptr, TOK, 3072, 1024);
  repack_kv<<<dim3(SEQ / 64, 32), 256, 0, stream>>>(qkvb, kT, vT);
  attn_kernel<<<dim3(32, SEQ / 64), 256, 0, stream>>>(qkvb, kT, vT, attnb);
  gemm_bt<1, 64><<<dim3(1024 / 64, TOK / 128), 256, 0, stream>>>(
      attnb, wprjT, x1, nullptr, b_proj, x, TOK, 1024, 1024);
  ln_kernel<<<TOK, 256, 0, stream>>>(x1, ln2_g, ln2_b, hb);
  gemm_bt<2, 128><<<dim3(4096 / 128, TOK / 128), 256, 0, stream>>>(
      hb, w1T, nullptr, hidb, b1, nullptr, TOK, 4096, 1024);
  gemm_bt<1, 64><<<dim3(1024 / 64, TOK / 128), 256, 0, stream>>>(
      hidb, w2T, out, nullptr, b2, x1, TOK, 1024, 4096);
}

// Round 5
// 389.657 us; speedup vs baseline: 1.3253x; 1.3253x over previous
//
#include <hip/hip_runtime.h>
#include <stdint.h>

// ---------------------------------------------------------------------------
// Transformer block: LN1 -> QKV GEMM -> repack K/V -> flash-MFMA attention
//                    -> proj(+res) -> LN2 -> MLP1(GELU) -> MLP2(+res)
// All matmuls: bf16 inputs, fp32 MFMA accumulation (16x16x32_bf16).
// Fragment layouts (learn_hip m89/m91):
//   A-frag:  A[m = lane&15][k = (lane>>4)*8 + j]   (8 bf16, contiguous in k)
//   B-frag:  B[k = (lane>>4)*8 + j][n = lane&15]   (= Bt[n][k], contiguous k)
//   C/D   :  D[m = (lane>>4)*4 + r][n = lane&15]
// Attention: S^T = K@Q^T, softmax rows per-lane (q = lane&15). 128 q/block,
// 32 q/wave (2 B-frag sets) so each staged K/V tile serves 2x the q rows.
// All LDS uses unpadded 128B rows with XOR chunk swizzle phys = log ^ (row&7)
// (R4-validated on the GEMM): swizzle applied on the global-source side of
// global_load_lds so LDS dests stay lane-linear; frag reads are <=2-way.
// ---------------------------------------------------------------------------

#define DIMC 1024
#define HIDN 4096
#define SEQ  2048
#define TOK  4096   // B*N = 2*2048

typedef __bf16 bf16x8 __attribute__((ext_vector_type(8)));
typedef float  f32x4  __attribute__((ext_vector_type(4)));
typedef unsigned short ushort8 __attribute__((ext_vector_type(8)));

__device__ inline unsigned short f2bf(float f) {
  union { float f; unsigned u; } v; v.f = f;
  unsigned u = v.u;
  return (unsigned short)((u + 0x7fffu + ((u >> 16) & 1u)) >> 16);  // RNE
}

// HW packed fp32->bf16 (CDNA3+): lo = cvt(a), hi = cvt(b)
__device__ inline unsigned cvt_pk_bf16(float a, float b) {
  unsigned r;
  asm("v_cvt_pk_bf16_f32 %0, %1, %2" : "=v"(r) : "v"(a), "v"(b));
  return r;
}

__device__ inline f32x4 mfma_bf16(bf16x8 a, bf16x8 b, f32x4 c) {
  return __builtin_amdgcn_mfma_f32_16x16x32_bf16(a, b, c, 0, 0, 0);
}

// async global->LDS, 16B per lane; LDS dest = wave-uniform base + lane*16
typedef const __attribute__((address_space(1))) unsigned int* as1_u32p;
typedef __attribute__((address_space(3))) unsigned int* as3_u32p;
__device__ inline void gload_lds16(const unsigned short* g, unsigned short* l) {
  __builtin_amdgcn_global_load_lds((as1_u32p)(const void*)g, (as3_u32p)(void*)l,
                                   16, 0, 0);
}

// ---------------------------------------------------------------------------
// All 4 weight transposes in one launch: w[K][N] fp32 -> wt[N][K] bf16
// ---------------------------------------------------------------------------
__global__ __launch_bounds__(256)
void transpose_cast4(const float* __restrict__ wa, unsigned short* __restrict__ ta,
                     const float* __restrict__ wb, unsigned short* __restrict__ tb,
                     const float* __restrict__ wc, unsigned short* __restrict__ tc,
                     const float* __restrict__ wd, unsigned short* __restrict__ td) {
  __shared__ float tile[32][33];
  const int bid = blockIdx.x;
  const float* w; unsigned short* wt; int K, N, bx, by;
  if (bid < 3072)      { w = wa; wt = ta; K = 1024; N = 3072; bx = bid % 96;  by = bid / 96; }
  else if (bid < 4096) { int i = bid - 3072; w = wb; wt = tb; K = 1024; N = 1024; bx = i % 32;  by = i / 32; }
  else if (bid < 8192) { int i = bid - 4096; w = wc; wt = tc; K = 1024; N = 4096; bx = i % 128; by = i / 128; }
  else                 { int i = bid - 8192; w = wd; wt = td; K = 4096; N = 1024; bx = i % 32;  by = i / 32; }
  const int k0 = by * 32;
  const int n0 = bx * 32;
  const int tx = threadIdx.x & 31;
  const int ty = threadIdx.x >> 5;  // 0..7
#pragma unroll
  for (int i = 0; i < 4; i++)
    tile[ty + i * 8][tx] = w[(size_t)(k0 + ty + i * 8) * N + n0 + tx];
  __syncthreads();
#pragma unroll
  for (int i = 0; i < 4; i++)
    wt[(size_t)(n0 + ty + i * 8) * K + k0 + tx] = f2bf(tile[tx][ty + i * 8]);
}

// ---------------------------------------------------------------------------
// LayerNorm: x[rows][1024] fp32 -> out bf16
// ---------------------------------------------------------------------------
__global__ __launch_bounds__(256)
void ln_kernel(const float* __restrict__ x, const float* __restrict__ g,
               const float* __restrict__ b, unsigned short* __restrict__ out) {
  const int row = blockIdx.x;
  const int tid = threadIdx.x;
  const float4* xr = (const float4*)&x[(size_t)row * DIMC];
  float4 v = xr[tid];
  float s  = v.x + v.y + v.z + v.w;
  float sq = v.x * v.x + v.y * v.y + v.z * v.z + v.w * v.w;
#pragma unroll
  for (int off = 32; off > 0; off >>= 1) {
    s  += __shfl_xor(s, off, 64);
    sq += __shfl_xor(sq, off, 64);
  }
  __shared__ float red[8];
  if ((tid & 63) == 0) { red[tid >> 6] = s; red[4 + (tid >> 6)] = sq; }
  __syncthreads();
  s  = red[0] + red[1] + red[2] + red[3];
  sq = red[4] + red[5] + red[6] + red[7];
  const float mu  = s * (1.0f / DIMC);
  const float var = sq * (1.0f / DIMC) - mu * mu;
  const float rs  = rsqrtf(var + 1e-5f);
  const int c = tid * 4;
  float vv[4] = {v.x, v.y, v.z, v.w};
#pragma unroll
  for (int j = 0; j < 4; j++)
    out[(size_t)row * DIMC + c + j] = f2bf((vv[j] - mu) * rs * g[c + j] + b[c + j]);
}

// ---------------------------------------------------------------------------
// GEMM: C[M][N] = A[M][K] @ B, Bt[N][K] bf16. 128xTN tile, BK=64, 4 waves.
// global_load_lds w16 staging; XOR chunk swizzle on the global source.
// EPI: 0 = bf16 store; 1 = +bias+res fp32; 2 = gelu(+bias) bf16
// ---------------------------------------------------------------------------
template <int EPI, int TN>
__global__ __launch_bounds__(256, (TN == 64) ? 4 : 2)
void gemm_bt(const unsigned short* __restrict__ A,
             const unsigned short* __restrict__ Bt,
             float* __restrict__ Cf, unsigned short* __restrict__ Cb,
             const float* __restrict__ bias, const float* __restrict__ res,
             int M, int N, int K) {
  constexpr int NU = TN / 32;            // B n-tiles per wave
  constexpr int BP = TN / 32;            // B staging passes (32 rows each)
  __shared__ unsigned short As[128 * 64];
  __shared__ unsigned short Bs[TN * 64];
  const int tid  = threadIdx.x;
  const int lane = tid & 63;
  const int wave = tid >> 6;
  const int m0 = blockIdx.y * 128;
  const int n0 = blockIdx.x * TN;
  const int wm = (wave >> 1) * 64;
  const int wn = (wave & 1) * (TN / 2);
  const int lm = lane & 15;
  const int lg = lane >> 4;
  const int r8 = tid >> 3;     // 0..31 row within pass
  const int c8 = tid & 7;      // phys 16B chunk within 128B row
  const int csrc = ((c8 ^ (r8 & 7)) * 8);  // logical elem offset (swizzled)

  const unsigned short* gA = &A [(size_t)(m0 + r8) * K + csrc];
  const unsigned short* gB = &Bt[(size_t)(n0 + r8) * K + csrc];

  f32x4 acc[4][NU];
#pragma unroll
  for (int t = 0; t < 4; t++)
#pragma unroll
    for (int u = 0; u < NU; u++) acc[t][u] = {0.f, 0.f, 0.f, 0.f};

  const int x0 = (lg ^ (lm & 7)) * 8;        // sub 0 phys chunk offset (elems)
  const int x1 = ((4 + lg) ^ (lm & 7)) * 8;  // sub 1

  for (int k0 = 0; k0 < K; k0 += 64) {
    __syncthreads();                 // prior tile's LDS reads done
#pragma unroll
    for (int p = 0; p < 4; p++)
      gload_lds16(gA + (size_t)p * 32 * K + k0, &As[p * 2048 + wave * 512]);
#pragma unroll
    for (int p = 0; p < BP; p++)
      gload_lds16(gB + (size_t)p * 32 * K + k0, &Bs[p * 2048 + wave * 512]);
    __syncthreads();                 // drains vmcnt before barrier
#pragma unroll
    for (int sub = 0; sub < 2; sub++) {
      const int xo = sub ? x1 : x0;
      bf16x8 af[4], bfr[NU];
#pragma unroll
      for (int t = 0; t < 4; t++)  af[t]  = *(const bf16x8*)&As[(wm + t * 16 + lm) * 64 + xo];
#pragma unroll
      for (int u = 0; u < NU; u++) bfr[u] = *(const bf16x8*)&Bs[(wn + u * 16 + lm) * 64 + xo];
#pragma unroll
      for (int t = 0; t < 4; t++)
#pragma unroll
        for (int u = 0; u < NU; u++)
          acc[t][u] = mfma_bf16(af[t], bfr[u], acc[t][u]);
    }
  }

#pragma unroll
  for (int t = 0; t < 4; t++) {
    const int row = m0 + wm + t * 16 + lg * 4;
#pragma unroll
    for (int u = 0; u < NU; u++) {
      const int col = n0 + wn + u * 16 + lm;
#pragma unroll
      for (int r = 0; r < 4; r++) {
        float v = acc[t][u][r];
        size_t idx = (size_t)(row + r) * N + col;
        if (EPI == 0) {
          Cb[idx] = f2bf(v);
        } else if (EPI == 1) {
          Cf[idx] = v + bias[col] + res[idx];
        } else {
          float xg = v + bias[col];
          Cb[idx] = f2bf(0.5f * xg * (1.0f + erff(xg * 0.70710678118654752f)));
        }
      }
    }
  }
}

// ---------------------------------------------------------------------------
// Repack K,V per head: kT[bh][key][d] (head-gather), vT[bh][d][key]
// (transpose via LDS). qkv[token][3072], K at +1024, V at +2048, head h*64.
// ---------------------------------------------------------------------------
__global__ __launch_bounds__(256)
void repack_kv(const unsigned short* __restrict__ qkv,
               unsigned short* __restrict__ kT, unsigned short* __restrict__ vT) {
  const int kt = blockIdx.x;
  const int bh = blockIdx.y;
  const int b = bh >> 4, h = bh & 15;
  const int tid = threadIdx.x;
  __shared__ unsigned short tile[64 * 72];
  const int tok = tid >> 2;       // 0..63
  const int ch  = tid & 3;        // chunks ch, ch+4 (8 d each)
  const size_t srow = (size_t)(b * SEQ + kt * 64 + tok) * 3072 + h * 64;
  // K: straight copy
  ushort8 ka = *(const ushort8*)&qkv[srow + 1024 + ch * 8];
  ushort8 kb = *(const ushort8*)&qkv[srow + 1024 + 32 + ch * 8];
  const size_t kdst = ((size_t)bh * SEQ + kt * 64 + tok) * 64;
  *(ushort8*)&kT[kdst + ch * 8] = ka;
  *(ushort8*)&kT[kdst + 32 + ch * 8] = kb;
  // V: transpose via LDS
  ushort8 va = *(const ushort8*)&qkv[srow + 2048 + ch * 8];
  ushort8 vb = *(const ushort8*)&qkv[srow + 2048 + 32 + ch * 8];
  *(ushort8*)&tile[tok * 72 + ch * 8] = va;
  *(ushort8*)&tile[tok * 72 + 32 + ch * 8] = vb;
  __syncthreads();
  const int d = tid >> 2;         // 0..63
  ushort8 o0, o1;
#pragma unroll
  for (int j = 0; j < 8; j++) {
    o0[j] = tile[(ch * 8 + j) * 72 + d];
    o1[j] = tile[((ch + 4) * 8 + j) * 72 + d];
  }
  const size_t vdst = ((size_t)bh * 64 + d) * SEQ + kt * 64;
  *(ushort8*)&vT[vdst + ch * 8] = o0;
  *(ushort8*)&vT[vdst + 32 + ch * 8] = o1;
}

// ---------------------------------------------------------------------------
// Flash attention, transposed scores. Block = (qt: 128 q-rows, bh); wave =
// 32 q-rows (2 B-frag sets). S^T = K@Q^T (A=Ks, B=Q regs); softmax per-lane
// (q = set*16+lm), log2 domain; O^T += V^T@P^T with va reused across sets.
// Ks/Vs staged via global_load_lds w16, source-side XOR swizzle; Ps per-wave.
// LDS 32 KB. 2-barrier k-loop.
// ---------------------------------------------------------------------------
__global__ __launch_bounds__(256)
void attn_kernel(const unsigned short* __restrict__ qkv,
                 const unsigned short* __restrict__ kT,
                 const unsigned short* __restrict__ vT,
                 unsigned short* __restrict__ out) {
  const int qt = blockIdx.x;       // 16 tiles of 128 q-rows
  const int bh = blockIdx.y;
  const int b  = bh >> 4;
  const int h  = bh & 15;
  const int tid  = threadIdx.x;
  const int lane = tid & 63;
  const int wave = tid >> 6;
  const int lm = lane & 15;
  const int lg = lane >> 4;

  __shared__ unsigned short Ks[64 * 64];      // [key][d], swizzled chunks
  __shared__ unsigned short Vs[64 * 64];      // [d][key], swizzled chunks
  __shared__ unsigned short Ps[4][32 * 64];   // per-wave P^T[q][key], swizzled

  const int qrow_base = b * SEQ + qt * 128 + wave * 32;
  bf16x8 qb[2][2];  // [set][khalf] B-frag: Q natural
#pragma unroll
  for (int s = 0; s < 2; s++)
#pragma unroll
    for (int c = 0; c < 2; c++)
      qb[s][c] = *(const bf16x8*)&qkv[(size_t)(qrow_base + s * 16 + lm) * 3072 +
                                      h * 64 + c * 32 + lg * 8];

  f32x4 o[4][2];   // O^T accum: [dtile][set], m=d, n=q
#pragma unroll
  for (int dt = 0; dt < 4; dt++)
#pragma unroll
    for (int s = 0; s < 2; s++) o[dt][s] = {0.f, 0.f, 0.f, 0.f};
  float mi[2] = {-1e30f, -1e30f}, li[2] = {0.f, 0.f};
  const float LC = 0.125f * 1.44269504088896f;  // scale * log2(e)

  const unsigned short* kbp = &kT[(size_t)bh * SEQ * 64];
  const unsigned short* vbp = &vT[(size_t)bh * 64 * SEQ];
  // staging: pass p covers rows p*32 + (tid>>3); phys chunk tid&7; logical
  // source chunk = phys ^ (row&7)  (p*32 doesn't affect row&7)
  const int srow = tid >> 3;                    // 0..31
  const int slog = ((tid & 7) ^ (srow & 7)) * 8;  // source elem offset
  // fragment phys-chunk offsets (elems): logical chunk c*4+lg, row&7 = lm&7
  const int xk0 = ((lg)     ^ (lm & 7)) * 8;    // khalf 0
  const int xk1 = ((4 + lg) ^ (lm & 7)) * 8;    // khalf 1

  for (int kt = 0; kt < SEQ / 64; kt++) {
    __syncthreads();   // prior tile's frag reads done
#pragma unroll
    for (int p = 0; p < 2; p++) {
      gload_lds16(&kbp[(size_t)kt * 4096 + (p * 32 + srow) * 64 + slog],
                  &Ks[p * 2048 + wave * 512]);
      gload_lds16(&vbp[(size_t)(p * 32 + srow) * SEQ + kt * 64 + slog],
                  &Vs[p * 2048 + wave * 512]);
    }
    __syncthreads();   // vmcnt drained before barrier

    // S^T[key][q]: 4 key-tiles x 2 q-sets; ka shared across sets
    f32x4 st[2][4];
#pragma unroll
    for (int u = 0; u < 4; u++) {
      bf16x8 ka0 = *(const bf16x8*)&Ks[(u * 16 + lm) * 64 + xk0];
      bf16x8 ka1 = *(const bf16x8*)&Ks[(u * 16 + lm) * 64 + xk1];
#pragma unroll
      for (int s = 0; s < 2; s++) {
        f32x4 z = {0.f, 0.f, 0.f, 0.f};
        z = mfma_bf16(ka0, qb[s][0], z);
        z = mfma_bf16(ka1, qb[s][1], z);
        st[s][u] = z;
      }
    }

    // online softmax per set, row = s*16+lm; in-lane reduce + shfl 16,32
#pragma unroll
    for (int s = 0; s < 2; s++) {
      float mx = -1e30f;
#pragma unroll
      for (int u = 0; u < 4; u++)
#pragma unroll
        for (int r = 0; r < 4; r++) mx = fmaxf(mx, st[s][u][r]);
      mx = fmaxf(mx, __shfl_xor(mx, 16, 64));
      mx = fmaxf(mx, __shfl_xor(mx, 32, 64));
      const float mnew = fmaxf(mi[s], mx * LC);
      const float alpha = exp2f(mi[s] - mnew);
      float ps = 0.f;
#pragma unroll
      for (int u = 0; u < 4; u++)
#pragma unroll
        for (int r = 0; r < 4; r++) {
          float p = exp2f(fmaf(st[s][u][r], LC, -mnew));
          st[s][u][r] = p;
          ps += p;
        }
      ps += __shfl_xor(ps, 16, 64);
      ps += __shfl_xor(ps, 32, 64);
      li[s] = li[s] * alpha + ps;
      mi[s] = mnew;
#pragma unroll
      for (int dt = 0; dt < 4; dt++) o[dt][s] *= alpha;

      // P^T (C-layout) -> Ps[q][key]: q = s*16+lm; chunk u*2+(lg>>1), swizzled
#pragma unroll
      for (int u = 0; u < 4; u++) {
        uint2 pk;
        pk.x = cvt_pk_bf16(st[s][u][0], st[s][u][1]);
        pk.y = cvt_pk_bf16(st[s][u][2], st[s][u][3]);
        const int phys = (u * 2 + (lg >> 1)) ^ (lm & 7);
        *(uint2*)&Ps[wave][(s * 16 + lm) * 64 + phys * 8 + (lg & 1) * 4] = pk;
      }
    }

    // O^T += V^T @ P^T : va loaded once per (kc,dt), reused for both sets
#pragma unroll
    for (int kc = 0; kc < 2; kc++) {
      const int xo = kc ? xk1 : xk0;
      bf16x8 pb[2];
#pragma unroll
      for (int s = 0; s < 2; s++)
        pb[s] = *(const bf16x8*)&Ps[wave][(s * 16 + lm) * 64 + xo];
#pragma unroll
      for (int dt = 0; dt < 4; dt++) {
        bf16x8 va = *(const bf16x8*)&Vs[(dt * 16 + lm) * 64 + xo];
#pragma unroll
        for (int s = 0; s < 2; s++)
          o[dt][s] = mfma_bf16(va, pb[s], o[dt][s]);
      }
    }
  }

#pragma unroll
  for (int s = 0; s < 2; s++) {
    const float inv = 1.0f / li[s];
#pragma unroll
    for (int dt = 0; dt < 4; dt++) {
      uint2 ok;
      ok.x = cvt_pk_bf16(o[dt][s][0] * inv, o[dt][s][1] * inv);
      ok.y = cvt_pk_bf16(o[dt][s][2] * inv, o[dt][s][3] * inv);
      *(uint2*)&out[(size_t)(qrow_base + s * 16 + lm) * DIMC + h * 64 +
                    dt * 16 + lg * 4] = ok;
    }
  }
}

// ---------------------------------------------------------------------------
extern "C" void kernel_launch(void* const* d_in, const int* in_sizes, int n_in,
                              void* d_out, int out_size, void* d_ws, size_t ws_size,
                              hipStream_t stream) {
  const float* x      = (const float*)d_in[0];
  const float* ln1_g  = (const float*)d_in[1];
  const float* ln1_b  = (const float*)d_in[2];
  const float* w_qkv  = (const float*)d_in[3];
  const float* w_proj = (const float*)d_in[4];
  const float* b_proj = (const float*)d_in[5];
  const float* ln2_g  = (const float*)d_in[6];
  const float* ln2_b  = (const float*)d_in[7];
  const float* w1     = (const float*)d_in[8];
  const float* b1     = (const float*)d_in[9];
  const float* w2     = (const float*)d_in[10];
  const float* b2     = (const float*)d_in[11];
  float* out = (float*)d_out;

  char* ws = (char*)d_ws;
  size_t off = 0;
  auto alloc = [&](size_t bytes) { void* p = ws + off; off += (bytes + 255) & ~(size_t)255; return p; };
  unsigned short* wqkvT = (unsigned short*)alloc((size_t)3072 * 1024 * 2);
  unsigned short* wprjT = (unsigned short*)alloc((size_t)1024 * 1024 * 2);
  unsigned short* w1T   = (unsigned short*)alloc((size_t)4096 * 1024 * 2);
  unsigned short* w2T   = (unsigned short*)alloc((size_t)1024 * 4096 * 2);
  unsigned short* hb    = (unsigned short*)alloc((size_t)TOK * 1024 * 2);
  unsigned short* qkvb  = (unsigned short*)alloc((size_t)TOK * 3072 * 2);
  unsigned short* attnb = (unsigned short*)alloc((size_t)TOK * 1024 * 2);
  float*          x1    = (float*)         alloc((size_t)TOK * 1024 * 4);
  unsigned short* hidb  = (unsigned short*)alloc((size_t)TOK * 4096 * 2);
  // kT/vT overlay hidb (32MB >= 16MB): attn finishes before MLP1 writes hidb
  unsigned short* kT = hidb;                              // 8 MB
  unsigned short* vT = hidb + (size_t)32 * SEQ * 64;      // 8 MB

  transpose_cast4<<<12288, 256, 0, stream>>>(w_qkv, wqkvT, w_proj, wprjT,
                                             w1, w1T, w2, w2T);
  ln_kernel<<<TOK, 256, 0, stream>>>(x, ln1_g, ln1_b, hb);
  gemm_bt<0, 128><<<dim3(3072 / 128, TOK / 128), 256, 0, stream>>>(
      hb, wqkvT, nullptr, qkvb, nullptr, nullptr, TOK, 3072, 1024);
  repack_kv<<<dim3(SEQ / 64, 32), 256, 0, stream>>>(qkvb, kT, vT);
  attn_kernel<<<dim3(SEQ / 128, 32), 256, 0, stream>>>(qkvb, kT, vT, attnb);
  gemm_bt<1, 64><<<dim3(1024 / 64, TOK / 128), 256, 0, stream>>>(
      attnb, wprjT, x1, nullptr, b_proj, x, TOK, 1024, 1024);
  ln_kernel<<<TOK, 256, 0, stream>>>(x1, ln2_g, ln2_b, hb);
  gemm_bt<2, 128><<<dim3(4096 / 128, TOK / 128), 256, 0, stream>>>(
      hb, w1T, nullptr, hidb, b1, nullptr, TOK, 4096, 1024);
  gemm_bt<1, 64><<<dim3(1024 / 64, TOK / 128), 256, 0, stream>>>(
      hidb, w2T, out, nullptr, b2, x1, TOK, 1024, 4096);
}

// Round 6
// 371.575 us; speedup vs baseline: 1.3898x; 1.0487x over previous
//
#include <hip/hip_runtime.h>
#include <stdint.h>

// ---------------------------------------------------------------------------
// Transformer block: LN1 -> QKV GEMM (Q pre-scaled) -> repack K/V -> flash
// attention (static-max softmax) -> proj(+res) -> LN2 -> MLP1(GELU) ->
// MLP2(+res). bf16 MFMA 16x16x32, fp32 accum.
// Fragment layouts (learn_hip m89/m91):
//   A-frag:  A[m = lane&15][k = (lane>>4)*8 + j]
//   B-frag:  B[k = (lane>>4)*8 + j][n = lane&15]  (= Bt[n][k])
//   C/D   :  D[m = (lane>>4)*4 + r][n = lane&15]
// Attention: S^T = K@Q^T, q = lane&15 per-lane rows. Q columns carry
// 0.125*log2(e) from the QKV epilogue; softmax is STATIC-MAX: p = exp2(s-8),
// per-lane li accumulated, single cross-lane reduce at the end (scores are
// bounded ~|4|, fp32 exp2 safe to 127 — no online max/rescale needed).
// All LDS: unpadded 128B rows, XOR chunk swizzle phys = log ^ (row&7),
// applied on the global-source side of global_load_lds (R4/R5-validated).
// XCD decode everywhere: bid&7 pins the reuse dimension (bh / y-stripe) so
// per-XCD working sets (~2-4 MB) stay L2-resident.
// ---------------------------------------------------------------------------

#define DIMC 1024
#define HIDN 4096
#define SEQ  2048
#define TOK  4096   // B*N = 2*2048

typedef __bf16 bf16x8 __attribute__((ext_vector_type(8)));
typedef float  f32x4  __attribute__((ext_vector_type(4)));
typedef unsigned short ushort8 __attribute__((ext_vector_type(8)));

__device__ inline unsigned short f2bf(float f) {
  union { float f; unsigned u; } v; v.f = f;
  unsigned u = v.u;
  return (unsigned short)((u + 0x7fffu + ((u >> 16) & 1u)) >> 16);  // RNE
}

// HW packed fp32->bf16 (CDNA3+): lo = cvt(a), hi = cvt(b)
__device__ inline unsigned cvt_pk_bf16(float a, float b) {
  unsigned r;
  asm("v_cvt_pk_bf16_f32 %0, %1, %2" : "=v"(r) : "v"(a), "v"(b));
  return r;
}

__device__ inline f32x4 mfma_bf16(bf16x8 a, bf16x8 b, f32x4 c) {
  return __builtin_amdgcn_mfma_f32_16x16x32_bf16(a, b, c, 0, 0, 0);
}

// async global->LDS, 16B per lane; LDS dest = wave-uniform base + lane*16
typedef const __attribute__((address_space(1))) unsigned int* as1_u32p;
typedef __attribute__((address_space(3))) unsigned int* as3_u32p;
__device__ inline void gload_lds16(const unsigned short* g, unsigned short* l) {
  __builtin_amdgcn_global_load_lds((as1_u32p)(const void*)g, (as3_u32p)(void*)l,
                                   16, 0, 0);
}

// ---------------------------------------------------------------------------
// All 4 weight transposes in one launch: w[K][N] fp32 -> wt[N][K] bf16
// ---------------------------------------------------------------------------
__global__ __launch_bounds__(256)
void transpose_cast4(const float* __restrict__ wa, unsigned short* __restrict__ ta,
                     const float* __restrict__ wb, unsigned short* __restrict__ tb,
                     const float* __restrict__ wc, unsigned short* __restrict__ tc,
                     const float* __restrict__ wd, unsigned short* __restrict__ td) {
  __shared__ float tile[32][33];
  const int bid = blockIdx.x;
  const float* w; unsigned short* wt; int K, N, bx, by;
  if (bid < 3072)      { w = wa; wt = ta; K = 1024; N = 3072; bx = bid % 96;  by = bid / 96; }
  else if (bid < 4096) { int i = bid - 3072; w = wb; wt = tb; K = 1024; N = 1024; bx = i % 32;  by = i / 32; }
  else if (bid < 8192) { int i = bid - 4096; w = wc; wt = tc; K = 1024; N = 4096; bx = i % 128; by = i / 128; }
  else                 { int i = bid - 8192; w = wd; wt = td; K = 4096; N = 1024; bx = i % 32;  by = i / 32; }
  const int k0 = by * 32;
  const int n0 = bx * 32;
  const int tx = threadIdx.x & 31;
  const int ty = threadIdx.x >> 5;  // 0..7
#pragma unroll
  for (int i = 0; i < 4; i++)
    tile[ty + i * 8][tx] = w[(size_t)(k0 + ty + i * 8) * N + n0 + tx];
  __syncthreads();
#pragma unroll
  for (int i = 0; i < 4; i++)
    wt[(size_t)(n0 + ty + i * 8) * K + k0 + tx] = f2bf(tile[tx][ty + i * 8]);
}

// ---------------------------------------------------------------------------
// LayerNorm: x[rows][1024] fp32 -> out bf16
// ---------------------------------------------------------------------------
__global__ __launch_bounds__(256)
void ln_kernel(const float* __restrict__ x, const float* __restrict__ g,
               const float* __restrict__ b, unsigned short* __restrict__ out) {
  const int row = blockIdx.x;
  const int tid = threadIdx.x;
  const float4* xr = (const float4*)&x[(size_t)row * DIMC];
  float4 v = xr[tid];
  float s  = v.x + v.y + v.z + v.w;
  float sq = v.x * v.x + v.y * v.y + v.z * v.z + v.w * v.w;
#pragma unroll
  for (int off = 32; off > 0; off >>= 1) {
    s  += __shfl_xor(s, off, 64);
    sq += __shfl_xor(sq, off, 64);
  }
  __shared__ float red[8];
  if ((tid & 63) == 0) { red[tid >> 6] = s; red[4 + (tid >> 6)] = sq; }
  __syncthreads();
  s  = red[0] + red[1] + red[2] + red[3];
  sq = red[4] + red[5] + red[6] + red[7];
  const float mu  = s * (1.0f / DIMC);
  const float var = sq * (1.0f / DIMC) - mu * mu;
  const float rs  = rsqrtf(var + 1e-5f);
  const int c = tid * 4;
  float vv[4] = {v.x, v.y, v.z, v.w};
#pragma unroll
  for (int j = 0; j < 4; j++)
    out[(size_t)row * DIMC + c + j] = f2bf((vv[j] - mu) * rs * g[c + j] + b[c + j]);
}

// ---------------------------------------------------------------------------
// GEMM: C[M][N] = A[M][K] @ B, Bt[N][K] bf16. 128xTN tile, BK=64, 4 waves.
// 1D grid with XCD decode: bid&7 = XCD, each XCD owns 4 consecutive
// y-stripes (A-reuse stays in its L2), x fastest within the stripe.
// EPI: 0 = bf16 store w/ Q-prescale (cols<1024 *= 0.125*log2e);
//      1 = +bias+res fp32; 2 = gelu(+bias) bf16
// ---------------------------------------------------------------------------
template <int EPI, int TN>
__global__ __launch_bounds__(256, (TN == 64) ? 4 : 2)
void gemm_bt(const unsigned short* __restrict__ A,
             const unsigned short* __restrict__ Bt,
             float* __restrict__ Cf, unsigned short* __restrict__ Cb,
             const float* __restrict__ bias, const float* __restrict__ res,
             int M, int N, int K) {
  constexpr int NU = TN / 32;            // B n-tiles per wave
  constexpr int BP = TN / 32;            // B staging passes (32 rows each)
  __shared__ unsigned short As[128 * 64];
  __shared__ unsigned short Bs[TN * 64];
  const int gx  = N / TN;                // x-tiles; gy = M/128 = 32 always
  const int bid = blockIdx.x;
  const int xcd = bid & 7;
  const int lin = bid >> 3;
  const int bx  = lin % gx;
  const int by  = (xcd << 2) + lin / gx;  // 4 y-stripes per XCD
  const int tid  = threadIdx.x;
  const int lane = tid & 63;
  const int wave = tid >> 6;
  const int m0 = by * 128;
  const int n0 = bx * TN;
  const int wm = (wave >> 1) * 64;
  const int wn = (wave & 1) * (TN / 2);
  const int lm = lane & 15;
  const int lg = lane >> 4;
  const int r8 = tid >> 3;     // 0..31 row within pass
  const int c8 = tid & 7;      // phys 16B chunk within 128B row
  const int csrc = ((c8 ^ (r8 & 7)) * 8);  // logical elem offset (swizzled)

  const unsigned short* gA = &A [(size_t)(m0 + r8) * K + csrc];
  const unsigned short* gB = &Bt[(size_t)(n0 + r8) * K + csrc];

  f32x4 acc[4][NU];
#pragma unroll
  for (int t = 0; t < 4; t++)
#pragma unroll
    for (int u = 0; u < NU; u++) acc[t][u] = {0.f, 0.f, 0.f, 0.f};

  const int x0 = (lg ^ (lm & 7)) * 8;        // sub 0 phys chunk offset (elems)
  const int x1 = ((4 + lg) ^ (lm & 7)) * 8;  // sub 1

  for (int k0 = 0; k0 < K; k0 += 64) {
    __syncthreads();                 // prior tile's LDS reads done
#pragma unroll
    for (int p = 0; p < 4; p++)
      gload_lds16(gA + (size_t)p * 32 * K + k0, &As[p * 2048 + wave * 512]);
#pragma unroll
    for (int p = 0; p < BP; p++)
      gload_lds16(gB + (size_t)p * 32 * K + k0, &Bs[p * 2048 + wave * 512]);
    __syncthreads();                 // drains vmcnt before barrier
#pragma unroll
    for (int sub = 0; sub < 2; sub++) {
      const int xo = sub ? x1 : x0;
      bf16x8 af[4], bfr[NU];
#pragma unroll
      for (int t = 0; t < 4; t++)  af[t]  = *(const bf16x8*)&As[(wm + t * 16 + lm) * 64 + xo];
#pragma unroll
      for (int u = 0; u < NU; u++) bfr[u] = *(const bf16x8*)&Bs[(wn + u * 16 + lm) * 64 + xo];
#pragma unroll
      for (int t = 0; t < 4; t++)
#pragma unroll
        for (int u = 0; u < NU; u++)
          acc[t][u] = mfma_bf16(af[t], bfr[u], acc[t][u]);
    }
  }

#pragma unroll
  for (int t = 0; t < 4; t++) {
    const int row = m0 + wm + t * 16 + lg * 4;
#pragma unroll
    for (int u = 0; u < NU; u++) {
      const int col = n0 + wn + u * 16 + lm;
#pragma unroll
      for (int r = 0; r < 4; r++) {
        float v = acc[t][u][r];
        size_t idx = (size_t)(row + r) * N + col;
        if (EPI == 0) {
          // QKV epilogue: fold scale*log2(e) into Q columns
          const float sc = (col < 1024) ? 0.18033688011112042f : 1.0f;
          Cb[idx] = f2bf(v * sc);
        } else if (EPI == 1) {
          Cf[idx] = v + bias[col] + res[idx];
        } else {
          float xg = v + bias[col];
          Cb[idx] = f2bf(0.5f * xg * (1.0f + erff(xg * 0.70710678118654752f)));
        }
      }
    }
  }
}

// ---------------------------------------------------------------------------
// Repack K,V per head: kT[bh][key][d] (head-gather), vT[bh][d][key]
// (transpose via LDS). qkv[token][3072], K at +1024, V at +2048, head h*64.
// ---------------------------------------------------------------------------
__global__ __launch_bounds__(256)
void repack_kv(const unsigned short* __restrict__ qkv,
               unsigned short* __restrict__ kT, unsigned short* __restrict__ vT) {
  const int kt = blockIdx.x;
  const int bh = blockIdx.y;
  const int b = bh >> 4, h = bh & 15;
  const int tid = threadIdx.x;
  __shared__ unsigned short tile[64 * 72];
  const int tok = tid >> 2;       // 0..63
  const int ch  = tid & 3;        // chunks ch, ch+4 (8 d each)
  const size_t srow = (size_t)(b * SEQ + kt * 64 + tok) * 3072 + h * 64;
  // K: straight copy
  ushort8 ka = *(const ushort8*)&qkv[srow + 1024 + ch * 8];
  ushort8 kb = *(const ushort8*)&qkv[srow + 1024 + 32 + ch * 8];
  const size_t kdst = ((size_t)bh * SEQ + kt * 64 + tok) * 64;
  *(ushort8*)&kT[kdst + ch * 8] = ka;
  *(ushort8*)&kT[kdst + 32 + ch * 8] = kb;
  // V: transpose via LDS
  ushort8 va = *(const ushort8*)&qkv[srow + 2048 + ch * 8];
  ushort8 vb = *(const ushort8*)&qkv[srow + 2048 + 32 + ch * 8];
  *(ushort8*)&tile[tok * 72 + ch * 8] = va;
  *(ushort8*)&tile[tok * 72 + 32 + ch * 8] = vb;
  __syncthreads();
  const int d = tid >> 2;         // 0..63
  ushort8 o0, o1;
#pragma unroll
  for (int j = 0; j < 8; j++) {
    o0[j] = tile[(ch * 8 + j) * 72 + d];
    o1[j] = tile[((ch + 4) * 8 + j) * 72 + d];
  }
  const size_t vdst = ((size_t)bh * 64 + d) * SEQ + kt * 64;
  *(ushort8*)&vT[vdst + ch * 8] = o0;
  *(ushort8*)&vT[vdst + 32 + ch * 8] = o1;
}

// ---------------------------------------------------------------------------
// Flash attention, transposed scores, STATIC-MAX softmax. Block = 64 q-rows;
// wave = 16 q-rows. 1D grid 1024, XCD decode: bid&7 pins bh group (4 bh per
// XCD -> 2 MB kT/vT working set, L2-resident). Ks/Vs via global_load_lds w16
// with source-side XOR swizzle; Ps per-wave. No shuffles / no rescale in the
// k-loop: p = exp2(s - 8), per-lane li, one cross-lane reduce at the end.
// LDS 24 KB.
// ---------------------------------------------------------------------------
__global__ __launch_bounds__(256)
void attn_kernel(const unsigned short* __restrict__ qkv,
                 const unsigned short* __restrict__ kT,
                 const unsigned short* __restrict__ vT,
                 unsigned short* __restrict__ out) {
  const int bid = blockIdx.x;
  const int xcd = bid & 7;
  const int lin = bid >> 3;         // 0..127
  const int bh  = (xcd << 2) + (lin >> 5);  // 4 bh per XCD
  const int qt  = lin & 31;
  const int b  = bh >> 4;
  const int h  = bh & 15;
  const int tid  = threadIdx.x;
  const int lane = tid & 63;
  const int wave = tid >> 6;
  const int lm = lane & 15;
  const int lg = lane >> 4;

  __shared__ unsigned short Ks[64 * 64];      // [key][d], swizzled chunks
  __shared__ unsigned short Vs[64 * 64];      // [d][key], swizzled chunks
  __shared__ unsigned short Ps[4][16 * 64];   // per-wave P^T[q][key], swizzled

  const int qrow_base = b * SEQ + qt * 64 + wave * 16;
  bf16x8 qb[2];  // B-frag: Q natural (pre-scaled by 0.125*log2e in QKV epi)
#pragma unroll
  for (int c = 0; c < 2; c++)
    qb[c] = *(const bf16x8*)&qkv[(size_t)(qrow_base + lm) * 3072 + h * 64 + c * 32 + lg * 8];

  f32x4 o[4];   // O^T accum: m = d (4 tiles of 16), n = q = lm
#pragma unroll
  for (int dt = 0; dt < 4; dt++) o[dt] = {0.f, 0.f, 0.f, 0.f};
  float li = 0.f;                    // per-lane partial sum (row lm)

  const unsigned short* kbp = &kT[(size_t)bh * SEQ * 64];
  const unsigned short* vbp = &vT[(size_t)bh * 64 * SEQ];
  const int srow = tid >> 3;                      // 0..31
  const int slog = ((tid & 7) ^ (srow & 7)) * 8;  // source elem offset
  const int xk0 = ((lg)     ^ (lm & 7)) * 8;      // frag phys offsets
  const int xk1 = ((4 + lg) ^ (lm & 7)) * 8;

  for (int kt = 0; kt < SEQ / 64; kt++) {
    __syncthreads();   // prior tile's frag reads done
#pragma unroll
    for (int p = 0; p < 2; p++) {
      gload_lds16(&kbp[(size_t)kt * 4096 + (p * 32 + srow) * 64 + slog],
                  &Ks[p * 2048 + wave * 512]);
      gload_lds16(&vbp[(size_t)(p * 32 + srow) * SEQ + kt * 64 + slog],
                  &Vs[p * 2048 + wave * 512]);
    }
    __syncthreads();   // vmcnt drained before barrier

    // S^T[key][q] (already includes 0.125*log2e via Q prescale)
    f32x4 st[4];
#pragma unroll
    for (int u = 0; u < 4; u++) {
      bf16x8 ka0 = *(const bf16x8*)&Ks[(u * 16 + lm) * 64 + xk0];
      bf16x8 ka1 = *(const bf16x8*)&Ks[(u * 16 + lm) * 64 + xk1];
      f32x4 z = {0.f, 0.f, 0.f, 0.f};
      z = mfma_bf16(ka0, qb[0], z);
      z = mfma_bf16(ka1, qb[1], z);
      st[u] = z;
    }

    // static-max softmax: p = exp2(s - 8); per-lane li; no shuffles here
#pragma unroll
    for (int u = 0; u < 4; u++)
#pragma unroll
      for (int r = 0; r < 4; r++) {
        float p = exp2f(st[u][r] - 8.0f);
        st[u][r] = p;
        li += p;
      }

    // P^T (C-layout) -> Ps[q=lm][key], swizzled chunks, b64 writes (in-wave)
#pragma unroll
    for (int u = 0; u < 4; u++) {
      uint2 pk;
      pk.x = cvt_pk_bf16(st[u][0], st[u][1]);
      pk.y = cvt_pk_bf16(st[u][2], st[u][3]);
      const int phys = (u * 2 + (lg >> 1)) ^ (lm & 7);
      *(uint2*)&Ps[wave][lm * 64 + phys * 8 + (lg & 1) * 4] = pk;
    }

    // O^T += V^T @ P^T
#pragma unroll
    for (int kc = 0; kc < 2; kc++) {
      const int xo = kc ? xk1 : xk0;
      bf16x8 pb = *(const bf16x8*)&Ps[wave][lm * 64 + xo];
#pragma unroll
      for (int dt = 0; dt < 4; dt++) {
        bf16x8 va = *(const bf16x8*)&Vs[(dt * 16 + lm) * 64 + xo];
        o[dt] = mfma_bf16(va, pb, o[dt]);
      }
    }
  }

  // single cross-lane reduce of li over the 4 key-groups (lg)
  li += __shfl_xor(li, 16, 64);
  li += __shfl_xor(li, 32, 64);
  const float inv = 1.0f / li;
#pragma unroll
  for (int dt = 0; dt < 4; dt++) {
    uint2 ok;
    ok.x = cvt_pk_bf16(o[dt][0] * inv, o[dt][1] * inv);
    ok.y = cvt_pk_bf16(o[dt][2] * inv, o[dt][3] * inv);
    *(uint2*)&out[(size_t)(qrow_base + lm) * DIMC + h * 64 + dt * 16 + lg * 4] = ok;
  }
}

// ---------------------------------------------------------------------------
extern "C" void kernel_launch(void* const* d_in, const int* in_sizes, int n_in,
                              void* d_out, int out_size, void* d_ws, size_t ws_size,
                              hipStream_t stream) {
  const float* x      = (const float*)d_in[0];
  const float* ln1_g  = (const float*)d_in[1];
  const float* ln1_b  = (const float*)d_in[2];
  const float* w_qkv  = (const float*)d_in[3];
  const float* w_proj = (const float*)d_in[4];
  const float* b_proj = (const float*)d_in[5];
  const float* ln2_g  = (const float*)d_in[6];
  const float* ln2_b  = (const float*)d_in[7];
  const float* w1     = (const float*)d_in[8];
  const float* b1     = (const float*)d_in[9];
  const float* w2     = (const float*)d_in[10];
  const float* b2     = (const float*)d_in[11];
  float* out = (float*)d_out;

  char* ws = (char*)d_ws;
  size_t off = 0;
  auto alloc = [&](size_t bytes) { void* p = ws + off; off += (bytes + 255) & ~(size_t)255; return p; };
  unsigned short* wqkvT = (unsigned short*)alloc((size_t)3072 * 1024 * 2);
  unsigned short* wprjT = (unsigned short*)alloc((size_t)1024 * 1024 * 2);
  unsigned short* w1T   = (unsigned short*)alloc((size_t)4096 * 1024 * 2);
  unsigned short* w2T   = (unsigned short*)alloc((size_t)1024 * 4096 * 2);
  unsigned short* hb    = (unsigned short*)alloc((size_t)TOK * 1024 * 2);
  unsigned short* qkvb  = (unsigned short*)alloc((size_t)TOK * 3072 * 2);
  unsigned short* attnb = (unsigned short*)alloc((size_t)TOK * 1024 * 2);
  float*          x1    = (float*)         alloc((size_t)TOK * 1024 * 4);
  unsigned short* hidb  = (unsigned short*)alloc((size_t)TOK * 4096 * 2);
  // kT/vT overlay hidb (32MB >= 16MB): attn finishes before MLP1 writes hidb
  unsigned short* kT = hidb;                              // 8 MB
  unsigned short* vT = hidb + (size_t)32 * SEQ * 64;      // 8 MB

  transpose_cast4<<<12288, 256, 0, stream>>>(w_qkv, wqkvT, w_proj, wprjT,
                                             w1, w1T, w2, w2T);
  ln_kernel<<<TOK, 256, 0, stream>>>(x, ln1_g, ln1_b, hb);
  gemm_bt<0, 128><<<768, 256, 0, stream>>>(       // QKV: gx=24, gy=32
      hb, wqkvT, nullptr, qkvb, nullptr, nullptr, TOK, 3072, 1024);
  repack_kv<<<dim3(SEQ / 64, 32), 256, 0, stream>>>(qkvb, kT, vT);
  attn_kernel<<<1024, 256, 0, stream>>>(qkvb, kT, vT, attnb);
  gemm_bt<1, 64><<<512, 256, 0, stream>>>(        // proj: gx=16, gy=32
      attnb, wprjT, x1, nullptr, b_proj, x, TOK, 1024, 1024);
  ln_kernel<<<TOK, 256, 0, stream>>>(x1, ln2_g, ln2_b, hb);
  gemm_bt<2, 128><<<1024, 256, 0, stream>>>(      // MLP1: gx=32, gy=32
      hb, w1T, nullptr, hidb, b1, nullptr, TOK, 4096, 1024);
  gemm_bt<1, 64><<<512, 256, 0, stream>>>(        // MLP2: gx=16, gy=32
      hidb, w2T, out, nullptr, b2, x1, TOK, 1024, 4096);
}